// Round 1
// 201.184 us; speedup vs baseline: 1.0326x; 1.0326x over previous
//
#include <hip/hip_runtime.h>
#include <math.h>

// InfiniAttention fused forward, MI355X round 13.
// B=4, N=2048, DIM=64, H=8, DH=64.
// Round-13 = round-12 with k_flash restructured for occupancy + LDS banks:
//   (a) 512 threads / 8 waves per block (grid is fixed at 512 blocks = 2/CU,
//       so 256-thr blocks capped the CU at 2 waves/SIMD -> 17% occupancy,
//       latency-bound: MfmaUtil 29 / VALU 40 / HBM 17, no pipe saturated).
//       Each wave now owns ONE 16-row strip; K/V staging still amortized
//       over the whole 128-row block. 4 waves/SIMD.
//   (b) V tile gets its own pitch KPV=68 (34 dwords == 2 mod 32): the PV
//       ds_read_b64 phases hit bank-starts {0,2,..,30} = all 32 banks once
//       (at KP=72 they hit even banks only -> 2x = ~4.2M of the 6.98M
//       SQ_LDS_BANK_CONFLICT). K stays at 72 (b128 phases need 4 mod 32).
//   (c) epilogue mem/Gv transpose-staging: b64 writes + coalesced f32 reads
//       (was scalar bf16 writes at 8-way conflict). Same values.
// All math bit-identical to round-12 (same MFMA order, same exp/lsum order).
//
// Workspace (floats, 16908288 total = 67,633,152 B):
//   kh   @ 0         f32  4194304
//   qb   @ 4194304   bf16 [bh][n][d]
//   kb   @ 6291456   bf16 [bh][n][d]  (pre-scaled by 0.1803...)
//   vb   @ 8388608   bf16 [bh][n][d]
//   vbT  @ 10485760  bf16 [bh][e][n]
//   Gv   @ 12582912  f32  131072  [bh][d][e]
//   pm   @ 12713984  f32  2097152 (16 chunks)  <- o bf16 aliases pm
//   pg   @ 14811136  f32  2097152

#define B_   4
#define N_   2048
#define H_   8
#define BH_  32
#define KP   72      // bf16 LDS pitch for K / Pw (144 B, b128-phase clean)
#define KPV  68      // bf16 LDS pitch for V tile (136 B, b64-phase clean)
#define SCLK 0.18033688f   // 0.125 * log2(e), folded into kb

typedef __bf16 bf16x8 __attribute__((ext_vector_type(8)));
typedef __bf16 bf16x4 __attribute__((ext_vector_type(4)));
typedef short  s16x4  __attribute__((ext_vector_type(4)));
typedef float  f32x4  __attribute__((ext_vector_type(4)));

__device__ __forceinline__ float eluf(float x) {
    return x > 0.0f ? x : expm1f(x);   // expm1 critical near 0
}

__device__ __forceinline__ float fexp2(float x) {
    return __builtin_amdgcn_exp2f(x);  // bare v_exp_f32 (inputs in normal range)
}

__device__ __forceinline__ f32x4 mfma16(bf16x4 a, bf16x4 b, f32x4 c) {
#if __has_builtin(__builtin_amdgcn_mfma_f32_16x16x16_bf16)
    return __builtin_amdgcn_mfma_f32_16x16x16_bf16(a, b, c, 0, 0, 0);
#else
    s16x4 ai, bi;
    __builtin_memcpy(&ai, &a, 8);
    __builtin_memcpy(&bi, &b, 8);
    return __builtin_amdgcn_mfma_f32_16x16x16bf16_1k(ai, bi, c, 0, 0, 0);
#endif
}

// ---------------- K2: head projections (unchanged from round-12 PASS) ---------
__global__ __launch_bounds__(256) void k_proj(
    const float* __restrict__ q, const float* __restrict__ k, const float* __restrict__ v,
    const float* __restrict__ Wq, const float* __restrict__ Wk, const float* __restrict__ Wv,
    __bf16* __restrict__ qb, float* __restrict__ kh, __bf16* __restrict__ kb,
    __bf16* __restrict__ vb, __bf16* __restrict__ vbT)
{
    const int which = blockIdx.z;
    const int h    = blockIdx.y;
    const int row0 = blockIdx.x * 64;   // over B*N = 8192
    const int tid  = threadIdx.x;
    const int b = row0 >> 11, nb = row0 & 2047;

    __shared__ __align__(16) float  AsT[64][68];   // [dim][row] (q/k path)
    __shared__ __align__(16) float  WsT[64][68];   // [dim][col] (q/k path)
    __shared__ __align__(16) __bf16 Cs[64 * 72];   // C bounce (v path)

    if (which == 2) {
        // ---- v: bf16 MFMA ----
        const int w = tid >> 6, lane = tid & 63;
        const int quad = lane >> 4, m = lane & 15;
        const float* ar = v + (size_t)(row0 + w * 16 + m) * 64;
        bf16x8 a0, a1;
        #pragma unroll
        for (int j = 0; j < 8; ++j) {
            a0[j] = (__bf16)ar[quad * 8 + j];
            a1[j] = (__bf16)ar[32 + quad * 8 + j];
        }
        f32x4 acc[4];
        #pragma unroll
        for (int t = 0; t < 4; ++t) {
            const float* wr = Wv + (size_t)(h * 64 + t * 16 + m) * 64;
            bf16x8 b0, b1;
            #pragma unroll
            for (int j = 0; j < 8; ++j) {
                b0[j] = (__bf16)wr[quad * 8 + j];
                b1[j] = (__bf16)wr[32 + quad * 8 + j];
            }
            f32x4 z = {0.f, 0.f, 0.f, 0.f};
            z = __builtin_amdgcn_mfma_f32_16x16x32_bf16(a0, b0, z, 0, 0, 0);
            acc[t] = __builtin_amdgcn_mfma_f32_16x16x32_bf16(a1, b1, z, 0, 0, 0);
        }
        #pragma unroll
        for (int t = 0; t < 4; ++t)
            #pragma unroll
            for (int r = 0; r < 4; ++r)
                Cs[(w * 16 + quad * 4 + r) * 72 + t * 16 + m] = (__bf16)acc[t][r];
        __syncthreads();
        // row-major -> vb
        const int rr = tid >> 2, csg = (tid & 3) * 16;
        bf16x8 r0 = *(const bf16x8*)&Cs[rr * 72 + csg];
        bf16x8 r1 = *(const bf16x8*)&Cs[rr * 72 + csg + 8];
        size_t gb = ((((size_t)b * H_ + h) * N_ + nb + rr) << 6) + csg;
        *(bf16x8*)&vb[gb]     = r0;
        *(bf16x8*)&vb[gb + 8] = r1;
        // col-major -> vbT
        const int e = tid >> 2, ns = (tid & 3) * 16;
        bf16x8 t0, t1;
        #pragma unroll
        for (int j = 0; j < 8; ++j) {
            t0[j] = Cs[(ns + j) * 72 + e];
            t1[j] = Cs[(ns + 8 + j) * 72 + e];
        }
        size_t base = (((size_t)b * H_ + h) * 64 + e) * (size_t)N_ + nb + ns;
        *(bf16x8*)&vbT[base]     = t0;
        *(bf16x8*)&vbT[base + 8] = t1;
        return;
    }

    // ---- q / k: exact f32 chain (byte-identical math to round-2..12 PASS) ----
    const float* __restrict__ src = (which == 0) ? q : k;
    const float* __restrict__ W   = (which == 0) ? Wq : Wk;
    for (int s = 0; s < 16; ++s) {
        int flat = s * 256 + tid;
        int r = flat >> 6, d = flat & 63;
        AsT[d][r] = src[(size_t)(row0 + r) * 64 + d];
        WsT[d][r] = W[(size_t)(h * 64 + r) * 64 + d];
    }
    __syncthreads();

    const int ty = tid >> 4, tx = tid & 15;
    float acc[4][4];
    #pragma unroll
    for (int i = 0; i < 4; ++i)
        #pragma unroll
        for (int j = 0; j < 4; ++j) acc[i][j] = 0.0f;
    for (int kd = 0; kd < 64; ++kd) {
        float4 a4 = *(const float4*)&AsT[kd][ty * 4];
        float4 w4 = *(const float4*)&WsT[kd][tx * 4];
        float a[4] = {a4.x, a4.y, a4.z, a4.w};
        float w[4] = {w4.x, w4.y, w4.z, w4.w};
        #pragma unroll
        for (int i = 0; i < 4; ++i)
            #pragma unroll
            for (int j = 0; j < 4; ++j) acc[i][j] = fmaf(a[i], w[j], acc[i][j]);
    }

    if (which == 0) {
        #pragma unroll
        for (int i = 0; i < 4; ++i) {
            size_t idx = ((((size_t)b * H_ + h) * N_ + nb + ty * 4 + i) << 6) + tx * 4;
            bf16x4 o4 = {(__bf16)acc[i][0], (__bf16)acc[i][1],
                         (__bf16)acc[i][2], (__bf16)acc[i][3]};
            *(bf16x4*)&qb[idx] = o4;
        }
    } else {
        #pragma unroll
        for (int i = 0; i < 4; ++i) {
            size_t idx = ((((size_t)b * H_ + h) * N_ + nb + ty * 4 + i) << 6) + tx * 4;
            *(float4*)&kh[idx] = make_float4(acc[i][0], acc[i][1], acc[i][2], acc[i][3]);
            bf16x4 o4 = {(__bf16)(acc[i][0] * SCLK), (__bf16)(acc[i][1] * SCLK),
                         (__bf16)(acc[i][2] * SCLK), (__bf16)(acc[i][3] * SCLK)};
            *(bf16x4*)&kb[idx] = o4;
        }
    }
}

// ---- K3: memory-update on split-bf16 MFMA (unchanged from round-12 PASS) ----
__global__ __launch_bounds__(256) void k_memacc(
    const float* __restrict__ kh, const __bf16* __restrict__ vb,
    const float* __restrict__ mem, const float* __restrict__ mem_norm,
    float* __restrict__ pmem, float* __restrict__ out_norm)
{
    const int chunk = blockIdx.x;    // 0..15
    const int bh    = blockIdx.y;
    const int h     = bh & 7;
    const int n0    = chunk * 128;

    __shared__ __align__(16) __bf16 memT_hi[64 * KP], memT_lo[64 * KP]; // [e][d]
    __shared__ __align__(16) __bf16 ekn_hi[64 * KP],  ekn_lo[64 * KP];  // [n][d]
    __shared__ __align__(16) __bf16 ekT_hi[64 * KP],  ekT_lo[64 * KP];  // [d][n]
    __shared__ __align__(16) __bf16 vtT_hi[64 * KP],  vtT_lo[64 * KP];  // [e][n]

    const int tid  = threadIdx.x;
    const int w    = tid >> 6, lane = tid & 63;
    const int quad = lane >> 4, m = lane & 15;

    for (int s = 0; s < 16; ++s) {
        int flat = s * 256 + tid;          // flat = d*64 + e
        int d = flat >> 6, e = flat & 63;
        float mv = mem[(size_t)h * 4096 + flat];
        __bf16 hi = (__bf16)mv;
        memT_hi[e * KP + d] = hi;
        memT_lo[e * KP + d] = (__bf16)(mv - (float)hi);
    }

    bf16x8 onesv;
    #pragma unroll
    for (int j = 0; j < 8; ++j) onesv[j] = (m == 0) ? (__bf16)1.0f : (__bf16)0.0f;

    f32x4 accM[4];
    #pragma unroll
    for (int t = 0; t < 4; ++t) { f32x4 z = {0.f, 0.f, 0.f, 0.f}; accM[t] = z; }
    __syncthreads();

    for (int sub = 0; sub < 2; ++sub) {
        const int nb = n0 + sub * 64;
        // ---- A1: ek exact f32, split hi/lo into natural + transposed ----
        for (int rr = w; rr < 64; rr += 4) {
            const int n = nb + rr;
            float ekv = eluf(kh[((size_t)bh * N_ + n) * 64 + lane]);
            __bf16 hi = (__bf16)ekv;
            __bf16 lo = (__bf16)(ekv - (float)hi);
            ekn_hi[rr * KP + lane] = hi;
            ekn_lo[rr * KP + lane] = lo;
            ekT_hi[lane * KP + rr] = hi;
            ekT_lo[lane * KP + rr] = lo;
        }
        __syncthreads();

        // ---- A2: km = ek@mem (3-pass) + out_norm (ones column) ----
        f32x4 km[4];
        #pragma unroll
        for (int t = 0; t < 4; ++t) { f32x4 z = {0.f, 0.f, 0.f, 0.f}; km[t] = z; }
        f32x4 nsum = {0.f, 0.f, 0.f, 0.f};
        #pragma unroll
        for (int c2 = 0; c2 < 2; ++c2) {
            bf16x8 Ah = *(const bf16x8*)&ekn_hi[(w * 16 + m) * KP + c2 * 32 + quad * 8];
            bf16x8 Al = *(const bf16x8*)&ekn_lo[(w * 16 + m) * KP + c2 * 32 + quad * 8];
            nsum = __builtin_amdgcn_mfma_f32_16x16x32_bf16(Ah, onesv, nsum, 0, 0, 0);
            nsum = __builtin_amdgcn_mfma_f32_16x16x32_bf16(Al, onesv, nsum, 0, 0, 0);
            #pragma unroll
            for (int et = 0; et < 4; ++et) {
                bf16x8 Bh = *(const bf16x8*)&memT_hi[(et * 16 + m) * KP + c2 * 32 + quad * 8];
                bf16x8 Bl = *(const bf16x8*)&memT_lo[(et * 16 + m) * KP + c2 * 32 + quad * 8];
                km[et] = __builtin_amdgcn_mfma_f32_16x16x32_bf16(Al, Bh, km[et], 0, 0, 0);
                km[et] = __builtin_amdgcn_mfma_f32_16x16x32_bf16(Ah, Bl, km[et], 0, 0, 0);
                km[et] = __builtin_amdgcn_mfma_f32_16x16x32_bf16(Ah, Bh, km[et], 0, 0, 0);
            }
        }
        if (m == 0) {
            #pragma unroll
            for (int r = 0; r < 4; ++r)
                out_norm[(size_t)bh * N_ + nb + w * 16 + quad * 4 + r] = nsum[r];
        }
        float nrmv[4];
        #pragma unroll
        for (int r = 0; r < 4; ++r)
            nrmv[r] = mem_norm[(size_t)h * N_ + nb + w * 16 + quad * 4 + r];
        #pragma unroll
        for (int et = 0; et < 4; ++et) {
            #pragma unroll
            for (int r = 0; r < 4; ++r) {
                const int nl = w * 16 + quad * 4 + r;
                const int e  = et * 16 + m;
                float vh  = (float)vb[((size_t)bh * N_ + nb + nl) * 64 + e];
                float ekv = (float)ekn_hi[nl * KP + e] + (float)ekn_lo[nl * KP + e];
                float vt  = vh - km[et][r] * __builtin_amdgcn_rcpf(ekv * nrmv[r]);
                __bf16 hi = (__bf16)vt;
                vtT_hi[e * KP + nl] = hi;
                vtT_lo[e * KP + nl] = (__bf16)(vt - (float)hi);
            }
        }
        __syncthreads();

        // ---- B: accM += ek^T @ v_term (3-pass MFMA) ----
        #pragma unroll
        for (int c2 = 0; c2 < 2; ++c2) {
            bf16x8 Ah = *(const bf16x8*)&ekT_hi[(w * 16 + m) * KP + c2 * 32 + quad * 8];
            bf16x8 Al = *(const bf16x8*)&ekT_lo[(w * 16 + m) * KP + c2 * 32 + quad * 8];
            #pragma unroll
            for (int et = 0; et < 4; ++et) {
                bf16x8 Bh = *(const bf16x8*)&vtT_hi[(et * 16 + m) * KP + c2 * 32 + quad * 8];
                bf16x8 Bl = *(const bf16x8*)&vtT_lo[(et * 16 + m) * KP + c2 * 32 + quad * 8];
                accM[et] = __builtin_amdgcn_mfma_f32_16x16x32_bf16(Al, Bh, accM[et], 0, 0, 0);
                accM[et] = __builtin_amdgcn_mfma_f32_16x16x32_bf16(Ah, Bl, accM[et], 0, 0, 0);
                accM[et] = __builtin_amdgcn_mfma_f32_16x16x32_bf16(Ah, Bh, accM[et], 0, 0, 0);
            }
        }
        __syncthreads();
    }

    const size_t base = ((size_t)chunk * BH_ + bh) * 4096;
    #pragma unroll
    for (int et = 0; et < 4; ++et)
        #pragma unroll
        for (int r = 0; r < 4; ++r)
            pmem[base + (size_t)(w * 16 + quad * 4 + r) * 64 + et * 16 + m] =
                accM[et][r];
}

// ---- K3g: Gv partials = Wg^T @ vh (unchanged from round-6 PASS) ----
__global__ __launch_bounds__(256) void k_gv(
    const float* __restrict__ Wg, const __bf16* __restrict__ vbT,
    float* __restrict__ pGv)
{
    const int chunk = blockIdx.x;    // 0..15
    const int bh    = blockIdx.y;
    const int n0    = chunk * 128;
    __shared__ __align__(16) __bf16 WgT[64 * 136];   // [d][n], pitch 272B
    const int tid  = threadIdx.x;
    const int w    = tid >> 6, lane = tid & 63;
    const int quad = lane >> 4, m = tid & 15;

    for (int s = 0; s < 8; ++s) {
        int f4 = s * 256 + tid;
        int n = f4 >> 4, dg = (f4 & 15) * 4;
        float4 wv = *(const float4*)&Wg[(size_t)(n0 + n) * 64 + dg];
        WgT[(dg + 0) * 136 + n] = (__bf16)wv.x;
        WgT[(dg + 1) * 136 + n] = (__bf16)wv.y;
        WgT[(dg + 2) * 136 + n] = (__bf16)wv.z;
        WgT[(dg + 3) * 136 + n] = (__bf16)wv.w;
    }
    __syncthreads();

    f32x4 acc[4];
    #pragma unroll
    for (int t = 0; t < 4; ++t) { f32x4 z = {0.f, 0.f, 0.f, 0.f}; acc[t] = z; }
    #pragma unroll
    for (int c = 0; c < 4; ++c) {
        bf16x8 Af = *(const bf16x8*)&WgT[(w * 16 + m) * 136 + c * 32 + quad * 8];
        #pragma unroll
        for (int et = 0; et < 4; ++et) {
            bf16x8 Bf = *(const bf16x8*)&vbT[((size_t)bh * 64 + et * 16 + m) * N_ +
                                             n0 + c * 32 + quad * 8];
            acc[et] = __builtin_amdgcn_mfma_f32_16x16x32_bf16(Af, Bf, acc[et], 0, 0, 0);
        }
    }
    const size_t base = ((size_t)chunk * BH_ + bh) * 4096;
    #pragma unroll
    for (int et = 0; et < 4; ++et)
        #pragma unroll
        for (int r = 0; r < 4; ++r)
            pGv[base + (size_t)(w * 16 + quad * 4 + r) * 64 + et * 16 + m] =
                acc[et][r];
}

// ---------------- K3b: reduce partials (unchanged) ----------------
__global__ __launch_bounds__(256) void k_reduce(
    const float* __restrict__ mem, const float* __restrict__ pmem,
    const float* __restrict__ pGv, float* __restrict__ out_mem, float* __restrict__ Gv)
{
    const int idx = blockIdx.x * 256 + threadIdx.x;
    const int bh = idx >> 12, h = bh & 7, de = idx & 4095;
    float sm = mem[(size_t)h * 4096 + de];
    float sg = 0.0f;
    #pragma unroll
    for (int c = 0; c < 16; ++c) {
        sm += pmem[(size_t)c * 131072 + idx];
        sg += pGv[(size_t)c * 131072 + idx];
    }
    out_mem[idx] = sm;
    Gv[idx] = sg;
}

// ---------- K4: flash attention, round-13: 8 waves, 1 strip/wave ----------
// 512 thr = 8 waves; 128-row blocks; wave owns 16 q-rows.
// Grid is fixed at 512 blocks (2/CU): 256-thr blocks gave 2 waves/SIMD and
// 17% occupancy -> latency-bound. 8 waves -> 4 waves/SIMD, same staging
// amortization. V tile pitch KPV=68 makes PV ds_read_b64 bank-clean.
__global__ __launch_bounds__(512, 4) void k_flash(
    const __bf16* __restrict__ qb, const __bf16* __restrict__ kb,
    const __bf16* __restrict__ vbT, const float* __restrict__ mem,
    const float* __restrict__ mem_norm, const float* __restrict__ Gv,
    const float* __restrict__ s_local_p, const float* __restrict__ s_long_p,
    __bf16* __restrict__ o)
{
    const int n0 = blockIdx.x * 128;
    const int bh = blockIdx.y;
    const int h  = bh & 7;
    const __bf16* __restrict__ kbp = kb  + (size_t)bh * N_ * 64;
    const __bf16* __restrict__ vtp = vbT + (size_t)bh * 64 * N_;

    __shared__ __align__(16) __bf16 Kb[64 * KP];    // [kcol][d] p72; epi: MT [e][d]
    __shared__ __align__(16) __bf16 VT[64 * KPV];   // [e][n]   p68; epi: GT [e][d]
    __shared__ __align__(16) __bf16 Pw[128 * KP];   // epilogue strips only
    __shared__ float lsl[128];
    __shared__ float nrm_l[128];

    const int tid  = threadIdx.x;
    const int w    = tid >> 6, lane = tid & 63;
    const int quad = lane >> 4, m = lane & 15;
    const float gl   = 1.0f - 1.0f / (1.0f + __expf(-s_local_p[0]));
    const float sigg = 1.0f / (1.0f + __expf(-s_long_p[0]));

    if (tid < 128) nrm_l[tid] = mem_norm[(size_t)h * N_ + n0 + tid];

    const size_t q0 = ((size_t)bh * N_ + n0 + w * 16 + m) * 64;
    bf16x8 qa00 = *(const bf16x8*)&qb[q0 + quad * 8];
    bf16x8 qa01 = *(const bf16x8*)&qb[q0 + 32 + quad * 8];

    f32x4 O0[4];
    #pragma unroll
    for (int t = 0; t < 4; ++t) { f32x4 z = {0.f, 0.f, 0.f, 0.f}; O0[t] = z; }
    float lsum0 = 0.f;
    const int prs = w * 16;

    // staging: 512 threads cover 64 rows x 8 col-groups of 8 bf16 (16 B)
    const int srow = tid >> 3, scg = (tid & 7) * 8;
    bf16x8 pk0 = *(const bf16x8*)&kbp[(size_t)srow * 64 + scg];
    bf16x8 pv0 = *(const bf16x8*)&vtp[(size_t)srow * N_ + scg];

    for (int c = 0; c < 32; ++c) {
        __syncthreads();
        *(bf16x8*)&Kb[srow * KP + scg]  = pk0;
        *(bf16x8*)&VT[srow * KPV + scg] = pv0;
        __syncthreads();
        if (c + 1 < 32) {
            const size_t kn = (size_t)((c + 1) * 64 + srow) * 64 + scg;
            const size_t vn = (size_t)srow * N_ + (c + 1) * 64 + scg;
            pk0 = *(const bf16x8*)&kbp[kn];
            pv0 = *(const bf16x8*)&vtp[vn];
        }

        // ---- S^T = K' Q^T (K pre-scaled by 0.125*log2e) ----
        f32x4 s0[4];
        #pragma unroll
        for (int t = 0; t < 4; ++t) {
            bf16x8 ka0 = *(const bf16x8*)&Kb[(t * 16 + m) * KP + quad * 8];
            bf16x8 ka1 = *(const bf16x8*)&Kb[(t * 16 + m) * KP + 32 + quad * 8];
            f32x4 z = {0.f, 0.f, 0.f, 0.f};
            z = __builtin_amdgcn_mfma_f32_16x16x32_bf16(ka0, qa00, z, 0, 0, 0);
            s0[t] = __builtin_amdgcn_mfma_f32_16x16x32_bf16(ka1, qa01, z, 0, 0, 0);
        }

        // ---- p = v_exp_f32(s); lsum; P A-frags stay in REGISTERS ----
        // C-layout of s0[t]: value for qrow=m, kcol = t*16 + quad*4 + r
        // == A-fragment of mfma_f32_16x16x16_bf16 (A[m][k=quad*4+j]).
        bf16x4 pa0[4];
        #pragma unroll
        for (int t = 0; t < 4; ++t) {
            float p0 = fexp2(s0[t][0]), p1 = fexp2(s0[t][1]);
            float p2 = fexp2(s0[t][2]), p3 = fexp2(s0[t][3]);
            lsum0 += p0 + p1 + p2 + p3;
            bf16x4 pk = {(__bf16)p0, (__bf16)p1, (__bf16)p2, (__bf16)p3};
            pa0[t] = pk;
        }

        // ---- O += P V via K=16 MFMAs; V B-frag: B[k=quad*4+j][n=m] ----
        #pragma unroll
        for (int t = 0; t < 4; ++t) {
            #pragma unroll
            for (int et = 0; et < 4; ++et) {
                bf16x4 vb4 = *(const bf16x4*)&VT[(et * 16 + m) * KPV + t * 16 + quad * 4];
                O0[et] = mfma16(pa0[t], vb4, O0[et]);
            }
        }
    }

    lsum0 += __shfl_xor(lsum0, 16, 64);
    lsum0 += __shfl_xor(lsum0, 32, 64);
    if (lane < 16) lsl[prs + lane] = lsum0;

    __syncthreads();
    {
        const float* mp = mem + (size_t)h * 4096;
        const float* gp = Gv + (size_t)bh * 4096;
        #pragma unroll
        for (int s2 = 0; s2 < 2; ++s2) {
            int idx = s2 * 512 + tid;          // e(64) x d-quad(16)
            int e = idx & 63, d4 = (idx >> 6) << 2;
            bf16x4 mv, gv;
            #pragma unroll
            for (int j = 0; j < 4; ++j) {
                mv[j] = (__bf16)mp[(size_t)(d4 + j) * 64 + e];
                gv[j] = (__bf16)gp[(size_t)(d4 + j) * 64 + e];
            }
            *(bf16x4*)&Kb[e * KP + d4]  = mv;
            *(bf16x4*)&VT[e * KPV + d4] = gv;
        }
    }
    __syncthreads();

    __bf16* op = o + ((size_t)bh * N_ + n0) * 64;
    {
        bf16x8 ea0, ea1;
        #pragma unroll
        for (int j = 0; j < 8; ++j) {
            ea0[j] = (__bf16)eluf((float)qa00[j]);
            ea1[j] = (__bf16)eluf((float)qa01[j]);
        }
        f32x4 num[4];
        #pragma unroll
        for (int t = 0; t < 4; ++t) {
            bf16x8 b0 = *(const bf16x8*)&Kb[(t * 16 + m) * KP + quad * 8];
            bf16x8 b1 = *(const bf16x8*)&Kb[(t * 16 + m) * KP + 32 + quad * 8];
            f32x4 z = {0.f, 0.f, 0.f, 0.f};
            z = __builtin_amdgcn_mfma_f32_16x16x32_bf16(ea0, b0, z, 0, 0, 0);
            num[t] = __builtin_amdgcn_mfma_f32_16x16x32_bf16(ea1, b1, z, 0, 0, 0);
        }
        *(bf16x8*)&Pw[(prs + m) * KP + quad * 8]      = ea0;
        *(bf16x8*)&Pw[(prs + m) * KP + 32 + quad * 8] = ea1;
        asm volatile("s_waitcnt lgkmcnt(0)" ::: "memory");
        float mq[4][4];
        #pragma unroll
        for (int t = 0; t < 4; ++t)
            #pragma unroll
            for (int r = 0; r < 4; ++r) {
                float eqv = (float)Pw[(prs + quad * 4 + r) * KP + t * 16 + m];
                mq[t][r] = num[t][r] / (eqv * nrm_l[prs + quad * 4 + r]);
            }
        #pragma unroll
        for (int t = 0; t < 4; ++t)
            #pragma unroll
            for (int r = 0; r < 4; ++r)
                Pw[(prs + quad * 4 + r) * KP + t * 16 + m] = (__bf16)mq[t][r];
        asm volatile("s_waitcnt lgkmcnt(0)" ::: "memory");
        bf16x8 ma0 = *(const bf16x8*)&Pw[(prs + m) * KP + quad * 8];
        bf16x8 ma1 = *(const bf16x8*)&Pw[(prs + m) * KP + 32 + quad * 8];

        #pragma unroll
        for (int t = 0; t < 4; ++t) {
            bf16x8 g0 = *(const bf16x8*)&VT[(t * 16 + m) * KPV + quad * 8];
            bf16x8 g1 = *(const bf16x8*)&VT[(t * 16 + m) * KPV + 32 + quad * 8];
            f32x4 z = {0.f, 0.f, 0.f, 0.f};
            z = __builtin_amdgcn_mfma_f32_16x16x32_bf16(ma0, g0, z, 0, 0, 0);
            f32x4 o2 = __builtin_amdgcn_mfma_f32_16x16x32_bf16(ma1, g1, z, 0, 0, 0);
            #pragma unroll
            for (int r = 0; r < 4; ++r) {
                const int qr = prs + quad * 4 + r;
                float val = O0[t][r] * (gl / lsl[qr]) + sigg * o2[r];
                op[(size_t)qr * 64 + t * 16 + m] = (__bf16)val;
            }
        }
    }
}

// ---------------- K5: output projection on MFMA (unchanged) ----------------
__global__ __launch_bounds__(256) void k_outproj(
    const __bf16* __restrict__ o, const float* __restrict__ Wo,
    const float* __restrict__ bo, float* __restrict__ out)
{
    const int row0 = blockIdx.x * 64;      // over B*N
    const int b = row0 >> 11, nb = row0 & 2047;
    __shared__ __align__(16) __bf16 WoS[64 * 40];   // [dout][k] per 32-k block
    const int tid  = threadIdx.x;
    const int w    = tid >> 6, lane = tid & 63;
    const int quad = lane >> 4, m = lane & 15;

    f32x4 acc[4];
    #pragma unroll
    for (int t = 0; t < 4; ++t) { f32x4 z = {0.f, 0.f, 0.f, 0.f}; acc[t] = z; }

    for (int kbk = 0; kbk < 16; ++kbk) {
        for (int s2 = 0; s2 < 8; ++s2) {
            int flat = s2 * 256 + tid;      // flat = n*32 + kk
            int n = flat >> 5, kk = flat & 31;
            WoS[n * 40 + kk] = (__bf16)Wo[(size_t)n * 512 + kbk * 32 + kk];
        }
        __syncthreads();
        const int hc = kbk >> 1;
        size_t arow = (((size_t)b * H_ + hc) * N_ + nb + w * 16 + m);
        bf16x8 af = *(const bf16x8*)&o[arow * 64 + (kbk & 1) * 32 + quad * 8];
        #pragma unroll
        for (int t = 0; t < 4; ++t) {
            bf16x8 bf_ = *(const bf16x8*)&WoS[(t * 16 + m) * 40 + quad * 8];
            acc[t] = __builtin_amdgcn_mfma_f32_16x16x32_bf16(af, bf_, acc[t], 0, 0, 0);
        }
        __syncthreads();
    }
    #pragma unroll
    for (int t = 0; t < 4; ++t) {
        float bias = bo[t * 16 + m];
        #pragma unroll
        for (int r = 0; r < 4; ++r)
            out[(size_t)(row0 + w * 16 + quad * 4 + r) * 64 + t * 16 + m] =
                acc[t][r] + bias;
    }
}

extern "C" void kernel_launch(void* const* d_in, const int* in_sizes, int n_in,
                              void* d_out, int out_size, void* d_ws, size_t ws_size,
                              hipStream_t stream)
{
    const float* q        = (const float*)d_in[0];
    const float* k        = (const float*)d_in[1];
    const float* v        = (const float*)d_in[2];
    const float* Wq       = (const float*)d_in[3];
    const float* Wk       = (const float*)d_in[4];
    const float* Wv       = (const float*)d_in[5];
    const float* Wo       = (const float*)d_in[6];
    const float* bo       = (const float*)d_in[7];
    const float* Wg       = (const float*)d_in[8];
    const float* s_local  = (const float*)d_in[9];
    const float* s_long   = (const float*)d_in[10];
    const float* mem      = (const float*)d_in[11];
    const float* mem_norm = (const float*)d_in[12];

    float* ws = (float*)d_ws;
    float*  kh  = ws;
    __bf16* qb  = (__bf16*)(ws + 4194304);
    __bf16* kb  = (__bf16*)(ws + 6291456);
    __bf16* vb  = (__bf16*)(ws + 8388608);
    __bf16* vbT = (__bf16*)(ws + 10485760);
    float*  Gv  = ws + 12582912;
    float*  pm  = ws + 12713984;
    float*  pg  = ws + 14811136;
    __bf16* o   = (__bf16*)(ws + 12713984);   // aliases pm (dead after k_reduce)

    float* out      = (float*)d_out;
    float* out_mem  = out + 524288;
    float* out_norm = out + 655360;

    k_proj   <<<dim3(128, 8, 3), 256, 0, stream>>>(q, k, v, Wq, Wk, Wv,
                                                   qb, kh, kb, vb, vbT);
    k_memacc <<<dim3(16, 32),    256, 0, stream>>>(kh, vb, mem, mem_norm,
                                                   pm, out_norm);
    k_gv     <<<dim3(16, 32),    256, 0, stream>>>(Wg, vbT, pg);
    k_reduce <<<dim3(512),       256, 0, stream>>>(mem, pm, pg, out_mem, Gv);
    k_flash  <<<dim3(16, 32),    512, 0, stream>>>(qb, kb, vbT, mem, mem_norm, Gv,
                                                   s_local, s_long, o);
    k_outproj<<<dim3(128),       256, 0, stream>>>(o, Wo, bo, out);
}

// Round 2
// 198.779 us; speedup vs baseline: 1.0451x; 1.0121x over previous
//
#include <hip/hip_runtime.h>
#include <math.h>

// InfiniAttention fused forward, MI355X round 14.
// B=4, N=2048, DIM=64, H=8, DH=64.
// Round-14 = round-13 with k_flash restructured for LDS-byte efficiency:
// r13 counters showed LDS-data-path-bound (~83% of wall): each wave read the
// FULL 8KB K + 8KB V tile per iter for only 16 q-rows of work. Fix: 256-row
// blocks, 8 waves x 32 q-rows (r12's proven 2-strip per-wave shape) -> K/V
// reads amortized over 2x rows = LDS bytes per unit work halved. Grid (8,32)
// = 256 blocks = 1/CU. Double-buffered K/V tiles with ONE barrier per iter
// (write-after-barrier overlaps compute; prefetch issued one iter ahead).
// Epilogue LDS aliases the dead loop buffers (56.8KB total static).
// All math bit-identical per q-row to round-12/13 (same MFMA/exp/lsum order).
//
// Workspace (floats, 16908288 total = 67,633,152 B):
//   kh   @ 0         f32  4194304
//   qb   @ 4194304   bf16 [bh][n][d]
//   kb   @ 6291456   bf16 [bh][n][d]  (pre-scaled by 0.1803...)
//   vb   @ 8388608   bf16 [bh][n][d]
//   vbT  @ 10485760  bf16 [bh][e][n]
//   Gv   @ 12582912  f32  131072  [bh][d][e]
//   pm   @ 12713984  f32  2097152 (16 chunks)  <- o bf16 aliases pm
//   pg   @ 14811136  f32  2097152

#define B_   4
#define N_   2048
#define H_   8
#define BH_  32
#define KP   72      // bf16 LDS pitch for K / Pw (144 B, b128-phase clean)
#define KPV  68      // bf16 LDS pitch for V tile (136 B, b64-phase clean)
#define SCLK 0.18033688f   // 0.125 * log2(e), folded into kb

typedef __bf16 bf16x8 __attribute__((ext_vector_type(8)));
typedef __bf16 bf16x4 __attribute__((ext_vector_type(4)));
typedef short  s16x4  __attribute__((ext_vector_type(4)));
typedef float  f32x4  __attribute__((ext_vector_type(4)));

__device__ __forceinline__ float eluf(float x) {
    return x > 0.0f ? x : expm1f(x);   // expm1 critical near 0
}

__device__ __forceinline__ float fexp2(float x) {
    return __builtin_amdgcn_exp2f(x);  // bare v_exp_f32 (inputs in normal range)
}

__device__ __forceinline__ f32x4 mfma16(bf16x4 a, bf16x4 b, f32x4 c) {
#if __has_builtin(__builtin_amdgcn_mfma_f32_16x16x16_bf16)
    return __builtin_amdgcn_mfma_f32_16x16x16_bf16(a, b, c, 0, 0, 0);
#else
    s16x4 ai, bi;
    __builtin_memcpy(&ai, &a, 8);
    __builtin_memcpy(&bi, &b, 8);
    return __builtin_amdgcn_mfma_f32_16x16x16bf16_1k(ai, bi, c, 0, 0, 0);
#endif
}

// ---------------- K2: head projections (unchanged from round-13 PASS) ---------
__global__ __launch_bounds__(256) void k_proj(
    const float* __restrict__ q, const float* __restrict__ k, const float* __restrict__ v,
    const float* __restrict__ Wq, const float* __restrict__ Wk, const float* __restrict__ Wv,
    __bf16* __restrict__ qb, float* __restrict__ kh, __bf16* __restrict__ kb,
    __bf16* __restrict__ vb, __bf16* __restrict__ vbT)
{
    const int which = blockIdx.z;
    const int h    = blockIdx.y;
    const int row0 = blockIdx.x * 64;   // over B*N = 8192
    const int tid  = threadIdx.x;
    const int b = row0 >> 11, nb = row0 & 2047;

    __shared__ __align__(16) float  AsT[64][68];   // [dim][row] (q/k path)
    __shared__ __align__(16) float  WsT[64][68];   // [dim][col] (q/k path)
    __shared__ __align__(16) __bf16 Cs[64 * 72];   // C bounce (v path)

    if (which == 2) {
        // ---- v: bf16 MFMA ----
        const int w = tid >> 6, lane = tid & 63;
        const int quad = lane >> 4, m = lane & 15;
        const float* ar = v + (size_t)(row0 + w * 16 + m) * 64;
        bf16x8 a0, a1;
        #pragma unroll
        for (int j = 0; j < 8; ++j) {
            a0[j] = (__bf16)ar[quad * 8 + j];
            a1[j] = (__bf16)ar[32 + quad * 8 + j];
        }
        f32x4 acc[4];
        #pragma unroll
        for (int t = 0; t < 4; ++t) {
            const float* wr = Wv + (size_t)(h * 64 + t * 16 + m) * 64;
            bf16x8 b0, b1;
            #pragma unroll
            for (int j = 0; j < 8; ++j) {
                b0[j] = (__bf16)wr[quad * 8 + j];
                b1[j] = (__bf16)wr[32 + quad * 8 + j];
            }
            f32x4 z = {0.f, 0.f, 0.f, 0.f};
            z = __builtin_amdgcn_mfma_f32_16x16x32_bf16(a0, b0, z, 0, 0, 0);
            acc[t] = __builtin_amdgcn_mfma_f32_16x16x32_bf16(a1, b1, z, 0, 0, 0);
        }
        #pragma unroll
        for (int t = 0; t < 4; ++t)
            #pragma unroll
            for (int r = 0; r < 4; ++r)
                Cs[(w * 16 + quad * 4 + r) * 72 + t * 16 + m] = (__bf16)acc[t][r];
        __syncthreads();
        // row-major -> vb
        const int rr = tid >> 2, csg = (tid & 3) * 16;
        bf16x8 r0 = *(const bf16x8*)&Cs[rr * 72 + csg];
        bf16x8 r1 = *(const bf16x8*)&Cs[rr * 72 + csg + 8];
        size_t gb = ((((size_t)b * H_ + h) * N_ + nb + rr) << 6) + csg;
        *(bf16x8*)&vb[gb]     = r0;
        *(bf16x8*)&vb[gb + 8] = r1;
        // col-major -> vbT
        const int e = tid >> 2, ns = (tid & 3) * 16;
        bf16x8 t0, t1;
        #pragma unroll
        for (int j = 0; j < 8; ++j) {
            t0[j] = Cs[(ns + j) * 72 + e];
            t1[j] = Cs[(ns + 8 + j) * 72 + e];
        }
        size_t base = (((size_t)b * H_ + h) * 64 + e) * (size_t)N_ + nb + ns;
        *(bf16x8*)&vbT[base]     = t0;
        *(bf16x8*)&vbT[base + 8] = t1;
        return;
    }

    // ---- q / k: exact f32 chain (byte-identical math to round-2..13 PASS) ----
    const float* __restrict__ src = (which == 0) ? q : k;
    const float* __restrict__ W   = (which == 0) ? Wq : Wk;
    for (int s = 0; s < 16; ++s) {
        int flat = s * 256 + tid;
        int r = flat >> 6, d = flat & 63;
        AsT[d][r] = src[(size_t)(row0 + r) * 64 + d];
        WsT[d][r] = W[(size_t)(h * 64 + r) * 64 + d];
    }
    __syncthreads();

    const int ty = tid >> 4, tx = tid & 15;
    float acc[4][4];
    #pragma unroll
    for (int i = 0; i < 4; ++i)
        #pragma unroll
        for (int j = 0; j < 4; ++j) acc[i][j] = 0.0f;
    for (int kd = 0; kd < 64; ++kd) {
        float4 a4 = *(const float4*)&AsT[kd][ty * 4];
        float4 w4 = *(const float4*)&WsT[kd][tx * 4];
        float a[4] = {a4.x, a4.y, a4.z, a4.w};
        float w[4] = {w4.x, w4.y, w4.z, w4.w};
        #pragma unroll
        for (int i = 0; i < 4; ++i)
            #pragma unroll
            for (int j = 0; j < 4; ++j) acc[i][j] = fmaf(a[i], w[j], acc[i][j]);
    }

    if (which == 0) {
        #pragma unroll
        for (int i = 0; i < 4; ++i) {
            size_t idx = ((((size_t)b * H_ + h) * N_ + nb + ty * 4 + i) << 6) + tx * 4;
            bf16x4 o4 = {(__bf16)acc[i][0], (__bf16)acc[i][1],
                         (__bf16)acc[i][2], (__bf16)acc[i][3]};
            *(bf16x4*)&qb[idx] = o4;
        }
    } else {
        #pragma unroll
        for (int i = 0; i < 4; ++i) {
            size_t idx = ((((size_t)b * H_ + h) * N_ + nb + ty * 4 + i) << 6) + tx * 4;
            *(float4*)&kh[idx] = make_float4(acc[i][0], acc[i][1], acc[i][2], acc[i][3]);
            bf16x4 o4 = {(__bf16)(acc[i][0] * SCLK), (__bf16)(acc[i][1] * SCLK),
                         (__bf16)(acc[i][2] * SCLK), (__bf16)(acc[i][3] * SCLK)};
            *(bf16x4*)&kb[idx] = o4;
        }
    }
}

// ---- K3: memory-update on split-bf16 MFMA (unchanged from round-13 PASS) ----
__global__ __launch_bounds__(256) void k_memacc(
    const float* __restrict__ kh, const __bf16* __restrict__ vb,
    const float* __restrict__ mem, const float* __restrict__ mem_norm,
    float* __restrict__ pmem, float* __restrict__ out_norm)
{
    const int chunk = blockIdx.x;    // 0..15
    const int bh    = blockIdx.y;
    const int h     = bh & 7;
    const int n0    = chunk * 128;

    __shared__ __align__(16) __bf16 memT_hi[64 * KP], memT_lo[64 * KP]; // [e][d]
    __shared__ __align__(16) __bf16 ekn_hi[64 * KP],  ekn_lo[64 * KP];  // [n][d]
    __shared__ __align__(16) __bf16 ekT_hi[64 * KP],  ekT_lo[64 * KP];  // [d][n]
    __shared__ __align__(16) __bf16 vtT_hi[64 * KP],  vtT_lo[64 * KP];  // [e][n]

    const int tid  = threadIdx.x;
    const int w    = tid >> 6, lane = tid & 63;
    const int quad = lane >> 4, m = lane & 15;

    for (int s = 0; s < 16; ++s) {
        int flat = s * 256 + tid;          // flat = d*64 + e
        int d = flat >> 6, e = flat & 63;
        float mv = mem[(size_t)h * 4096 + flat];
        __bf16 hi = (__bf16)mv;
        memT_hi[e * KP + d] = hi;
        memT_lo[e * KP + d] = (__bf16)(mv - (float)hi);
    }

    bf16x8 onesv;
    #pragma unroll
    for (int j = 0; j < 8; ++j) onesv[j] = (m == 0) ? (__bf16)1.0f : (__bf16)0.0f;

    f32x4 accM[4];
    #pragma unroll
    for (int t = 0; t < 4; ++t) { f32x4 z = {0.f, 0.f, 0.f, 0.f}; accM[t] = z; }
    __syncthreads();

    for (int sub = 0; sub < 2; ++sub) {
        const int nb = n0 + sub * 64;
        // ---- A1: ek exact f32, split hi/lo into natural + transposed ----
        for (int rr = w; rr < 64; rr += 4) {
            const int n = nb + rr;
            float ekv = eluf(kh[((size_t)bh * N_ + n) * 64 + lane]);
            __bf16 hi = (__bf16)ekv;
            __bf16 lo = (__bf16)(ekv - (float)hi);
            ekn_hi[rr * KP + lane] = hi;
            ekn_lo[rr * KP + lane] = lo;
            ekT_hi[lane * KP + rr] = hi;
            ekT_lo[lane * KP + rr] = lo;
        }
        __syncthreads();

        // ---- A2: km = ek@mem (3-pass) + out_norm (ones column) ----
        f32x4 km[4];
        #pragma unroll
        for (int t = 0; t < 4; ++t) { f32x4 z = {0.f, 0.f, 0.f, 0.f}; km[t] = z; }
        f32x4 nsum = {0.f, 0.f, 0.f, 0.f};
        #pragma unroll
        for (int c2 = 0; c2 < 2; ++c2) {
            bf16x8 Ah = *(const bf16x8*)&ekn_hi[(w * 16 + m) * KP + c2 * 32 + quad * 8];
            bf16x8 Al = *(const bf16x8*)&ekn_lo[(w * 16 + m) * KP + c2 * 32 + quad * 8];
            nsum = __builtin_amdgcn_mfma_f32_16x16x32_bf16(Ah, onesv, nsum, 0, 0, 0);
            nsum = __builtin_amdgcn_mfma_f32_16x16x32_bf16(Al, onesv, nsum, 0, 0, 0);
            #pragma unroll
            for (int et = 0; et < 4; ++et) {
                bf16x8 Bh = *(const bf16x8*)&memT_hi[(et * 16 + m) * KP + c2 * 32 + quad * 8];
                bf16x8 Bl = *(const bf16x8*)&memT_lo[(et * 16 + m) * KP + c2 * 32 + quad * 8];
                km[et] = __builtin_amdgcn_mfma_f32_16x16x32_bf16(Al, Bh, km[et], 0, 0, 0);
                km[et] = __builtin_amdgcn_mfma_f32_16x16x32_bf16(Ah, Bl, km[et], 0, 0, 0);
                km[et] = __builtin_amdgcn_mfma_f32_16x16x32_bf16(Ah, Bh, km[et], 0, 0, 0);
            }
        }
        if (m == 0) {
            #pragma unroll
            for (int r = 0; r < 4; ++r)
                out_norm[(size_t)bh * N_ + nb + w * 16 + quad * 4 + r] = nsum[r];
        }
        float nrmv[4];
        #pragma unroll
        for (int r = 0; r < 4; ++r)
            nrmv[r] = mem_norm[(size_t)h * N_ + nb + w * 16 + quad * 4 + r];
        #pragma unroll
        for (int et = 0; et < 4; ++et) {
            #pragma unroll
            for (int r = 0; r < 4; ++r) {
                const int nl = w * 16 + quad * 4 + r;
                const int e  = et * 16 + m;
                float vh  = (float)vb[((size_t)bh * N_ + nb + nl) * 64 + e];
                float ekv = (float)ekn_hi[nl * KP + e] + (float)ekn_lo[nl * KP + e];
                float vt  = vh - km[et][r] * __builtin_amdgcn_rcpf(ekv * nrmv[r]);
                __bf16 hi = (__bf16)vt;
                vtT_hi[e * KP + nl] = hi;
                vtT_lo[e * KP + nl] = (__bf16)(vt - (float)hi);
            }
        }
        __syncthreads();

        // ---- B: accM += ek^T @ v_term (3-pass MFMA) ----
        #pragma unroll
        for (int c2 = 0; c2 < 2; ++c2) {
            bf16x8 Ah = *(const bf16x8*)&ekT_hi[(w * 16 + m) * KP + c2 * 32 + quad * 8];
            bf16x8 Al = *(const bf16x8*)&ekT_lo[(w * 16 + m) * KP + c2 * 32 + quad * 8];
            #pragma unroll
            for (int et = 0; et < 4; ++et) {
                bf16x8 Bh = *(const bf16x8*)&vtT_hi[(et * 16 + m) * KP + c2 * 32 + quad * 8];
                bf16x8 Bl = *(const bf16x8*)&vtT_lo[(et * 16 + m) * KP + c2 * 32 + quad * 8];
                accM[et] = __builtin_amdgcn_mfma_f32_16x16x32_bf16(Al, Bh, accM[et], 0, 0, 0);
                accM[et] = __builtin_amdgcn_mfma_f32_16x16x32_bf16(Ah, Bl, accM[et], 0, 0, 0);
                accM[et] = __builtin_amdgcn_mfma_f32_16x16x32_bf16(Ah, Bh, accM[et], 0, 0, 0);
            }
        }
        __syncthreads();
    }

    const size_t base = ((size_t)chunk * BH_ + bh) * 4096;
    #pragma unroll
    for (int et = 0; et < 4; ++et)
        #pragma unroll
        for (int r = 0; r < 4; ++r)
            pmem[base + (size_t)(w * 16 + quad * 4 + r) * 64 + et * 16 + m] =
                accM[et][r];
}

// ---- K3g: Gv partials = Wg^T @ vh (unchanged from round-6 PASS) ----
__global__ __launch_bounds__(256) void k_gv(
    const float* __restrict__ Wg, const __bf16* __restrict__ vbT,
    float* __restrict__ pGv)
{
    const int chunk = blockIdx.x;    // 0..15
    const int bh    = blockIdx.y;
    const int n0    = chunk * 128;
    __shared__ __align__(16) __bf16 WgT[64 * 136];   // [d][n], pitch 272B
    const int tid  = threadIdx.x;
    const int w    = tid >> 6, lane = tid & 63;
    const int quad = lane >> 4, m = tid & 15;

    for (int s = 0; s < 8; ++s) {
        int f4 = s * 256 + tid;
        int n = f4 >> 4, dg = (f4 & 15) * 4;
        float4 wv = *(const float4*)&Wg[(size_t)(n0 + n) * 64 + dg];
        WgT[(dg + 0) * 136 + n] = (__bf16)wv.x;
        WgT[(dg + 1) * 136 + n] = (__bf16)wv.y;
        WgT[(dg + 2) * 136 + n] = (__bf16)wv.z;
        WgT[(dg + 3) * 136 + n] = (__bf16)wv.w;
    }
    __syncthreads();

    f32x4 acc[4];
    #pragma unroll
    for (int t = 0; t < 4; ++t) { f32x4 z = {0.f, 0.f, 0.f, 0.f}; acc[t] = z; }
    #pragma unroll
    for (int c = 0; c < 4; ++c) {
        bf16x8 Af = *(const bf16x8*)&WgT[(w * 16 + m) * 136 + c * 32 + quad * 8];
        #pragma unroll
        for (int et = 0; et < 4; ++et) {
            bf16x8 Bf = *(const bf16x8*)&vbT[((size_t)bh * 64 + et * 16 + m) * N_ +
                                             n0 + c * 32 + quad * 8];
            acc[et] = __builtin_amdgcn_mfma_f32_16x16x32_bf16(Af, Bf, acc[et], 0, 0, 0);
        }
    }
    const size_t base = ((size_t)chunk * BH_ + bh) * 4096;
    #pragma unroll
    for (int et = 0; et < 4; ++et)
        #pragma unroll
        for (int r = 0; r < 4; ++r)
            pGv[base + (size_t)(w * 16 + quad * 4 + r) * 64 + et * 16 + m] =
                acc[et][r];
}

// ---------------- K3b: reduce partials (unchanged) ----------------
__global__ __launch_bounds__(256) void k_reduce(
    const float* __restrict__ mem, const float* __restrict__ pmem,
    const float* __restrict__ pGv, float* __restrict__ out_mem, float* __restrict__ Gv)
{
    const int idx = blockIdx.x * 256 + threadIdx.x;
    const int bh = idx >> 12, h = bh & 7, de = idx & 4095;
    float sm = mem[(size_t)h * 4096 + de];
    float sg = 0.0f;
    #pragma unroll
    for (int c = 0; c < 16; ++c) {
        sm += pmem[(size_t)c * 131072 + idx];
        sg += pGv[(size_t)c * 131072 + idx];
    }
    out_mem[idx] = sm;
    Gv[idx] = sg;
}

// ---------- K4: flash attention, round-14: 256-row blocks, 8 waves x 32 rows ----
// r13 was LDS-byte-bound: 288KB LDS reads per CU-iter-pair (every wave reads
// the full K+V tile for 16 rows of work) ~= the measured 4670-cyc wall.
// Now each wave owns 32 q-rows (two 16-row strips): K/V fragment reads are
// shared across both strips -> LDS bytes per unit work halved. Grid (8,32)
// = 256 blocks = 1 block/CU, 8 waves. Double-buffered K/V + single barrier
// per iter; global prefetch issued one iter ahead (covers full compute).
__global__ __launch_bounds__(512, 2) void k_flash(
    const __bf16* __restrict__ qb, const __bf16* __restrict__ kb,
    const __bf16* __restrict__ vbT, const float* __restrict__ mem,
    const float* __restrict__ mem_norm, const float* __restrict__ Gv,
    const float* __restrict__ s_local_p, const float* __restrict__ s_long_p,
    __bf16* __restrict__ o)
{
    const int n0 = blockIdx.x * 256;
    const int bh = blockIdx.y;
    const int h  = bh & 7;
    const __bf16* __restrict__ kbp = kb  + (size_t)bh * N_ * 64;
    const __bf16* __restrict__ vtp = vbT + (size_t)bh * 64 * N_;

    // LDS plan (56832 B static):
    //   loop:     KbA@0 (9216) KbB@9216 (9216) VTA@18432 (8704) VTB@27136 (8704)
    //   epilogue: MT@0 (9216)  GT@9216 (8704)  Pw@17920 (36864)   [aliases loop bufs]
    //   always:   lsl@54784 (1024) nrm_l@55808 (1024)
    __shared__ __align__(16) char smem[56832];
    __bf16* const KbA = (__bf16*)(smem);
    __bf16* const KbB = (__bf16*)(smem + 9216);
    __bf16* const VTA = (__bf16*)(smem + 18432);
    __bf16* const VTB = (__bf16*)(smem + 27136);
    __bf16* const MT  = (__bf16*)(smem);
    __bf16* const GT  = (__bf16*)(smem + 9216);
    __bf16* const Pw  = (__bf16*)(smem + 17920);
    float*  const lsl   = (float*)(smem + 54784);
    float*  const nrm_l = (float*)(smem + 55808);

    const int tid  = threadIdx.x;
    const int w    = tid >> 6, lane = tid & 63;
    const int quad = lane >> 4, m = lane & 15;
    const float gl   = 1.0f - 1.0f / (1.0f + __expf(-s_local_p[0]));
    const float sigg = 1.0f / (1.0f + __expf(-s_long_p[0]));

    if (tid < 256) nrm_l[tid] = mem_norm[(size_t)h * N_ + n0 + tid];

    const size_t q0 = ((size_t)bh * N_ + n0 + w * 32 + m) * 64;
    const size_t q1 = q0 + 16 * 64;
    bf16x8 qa00 = *(const bf16x8*)&qb[q0 + quad * 8];
    bf16x8 qa01 = *(const bf16x8*)&qb[q0 + 32 + quad * 8];
    bf16x8 qa10 = *(const bf16x8*)&qb[q1 + quad * 8];
    bf16x8 qa11 = *(const bf16x8*)&qb[q1 + 32 + quad * 8];

    f32x4 O0[4], O1[4];
    #pragma unroll
    for (int t = 0; t < 4; ++t) {
        f32x4 z = {0.f, 0.f, 0.f, 0.f};
        O0[t] = z; O1[t] = z;
    }
    float lsum0 = 0.f, lsum1 = 0.f;
    const int pr0 = w * 32, pr1 = w * 32 + 16;

    // staging: 512 threads cover 64 rows x 8 col-groups of 8 bf16 (16 B)
    const int srow = tid >> 3, scg = (tid & 7) * 8;
    bf16x8 pk0 = *(const bf16x8*)&kbp[(size_t)srow * 64 + scg];
    bf16x8 pv0 = *(const bf16x8*)&vtp[(size_t)srow * N_ + scg];
    *(bf16x8*)&KbA[srow * KP + scg]  = pk0;
    *(bf16x8*)&VTA[srow * KPV + scg] = pv0;
    {   // prefetch tile 1 (consumed by the write at c=0)
        const size_t kn = (size_t)(64 + srow) * 64 + scg;
        const size_t vn = (size_t)srow * N_ + 64 + scg;
        pk0 = *(const bf16x8*)&kbp[kn];
        pv0 = *(const bf16x8*)&vtp[vn];
    }

    for (int c = 0; c < 32; ++c) {
        __syncthreads();   // tile c visible; buf[(c+1)&1] fully drained (read in c-1)
        if (c + 1 < 32) {  // write tile c+1 (already in regs) overlapping compute of c
            __bf16* Kn = (c & 1) ? KbA : KbB;
            __bf16* Vn = (c & 1) ? VTA : VTB;
            *(bf16x8*)&Kn[srow * KP + scg]  = pk0;
            *(bf16x8*)&Vn[srow * KPV + scg] = pv0;
        }
        if (c + 2 < 32) {  // issue prefetch of tile c+2 (consumed next iter)
            const size_t kn = (size_t)((c + 2) * 64 + srow) * 64 + scg;
            const size_t vn = (size_t)srow * N_ + (c + 2) * 64 + scg;
            pk0 = *(const bf16x8*)&kbp[kn];
            pv0 = *(const bf16x8*)&vtp[vn];
        }
        const __bf16* Kc = (c & 1) ? KbB : KbA;
        const __bf16* Vc = (c & 1) ? VTB : VTA;

        // ---- S^T = K' Q^T, both strips (K pre-scaled by 0.125*log2e) ----
        f32x4 s0[4], s1[4];
        #pragma unroll
        for (int t = 0; t < 4; ++t) {
            bf16x8 ka0 = *(const bf16x8*)&Kc[(t * 16 + m) * KP + quad * 8];
            bf16x8 ka1 = *(const bf16x8*)&Kc[(t * 16 + m) * KP + 32 + quad * 8];
            f32x4 z = {0.f, 0.f, 0.f, 0.f};
            z = __builtin_amdgcn_mfma_f32_16x16x32_bf16(ka0, qa00, z, 0, 0, 0);
            s0[t] = __builtin_amdgcn_mfma_f32_16x16x32_bf16(ka1, qa01, z, 0, 0, 0);
            f32x4 z2 = {0.f, 0.f, 0.f, 0.f};
            z2 = __builtin_amdgcn_mfma_f32_16x16x32_bf16(ka0, qa10, z2, 0, 0, 0);
            s1[t] = __builtin_amdgcn_mfma_f32_16x16x32_bf16(ka1, qa11, z2, 0, 0, 0);
        }

        // ---- p = v_exp_f32(s); lsum; P A-frags stay in REGISTERS ----
        // C-layout of s0[t]: value for qrow=m, kcol = t*16 + quad*4 + r
        // == A-fragment of mfma_f32_16x16x16_bf16 (A[m][k=quad*4+j]).
        bf16x4 pa0[4], pa1[4];
        #pragma unroll
        for (int t = 0; t < 4; ++t) {
            float p0 = fexp2(s0[t][0]), p1 = fexp2(s0[t][1]);
            float p2 = fexp2(s0[t][2]), p3 = fexp2(s0[t][3]);
            lsum0 += p0 + p1 + p2 + p3;
            bf16x4 pk = {(__bf16)p0, (__bf16)p1, (__bf16)p2, (__bf16)p3};
            pa0[t] = pk;
            float r0 = fexp2(s1[t][0]), r1 = fexp2(s1[t][1]);
            float r2 = fexp2(s1[t][2]), r3 = fexp2(s1[t][3]);
            lsum1 += r0 + r1 + r2 + r3;
            bf16x4 rk = {(__bf16)r0, (__bf16)r1, (__bf16)r2, (__bf16)r3};
            pa1[t] = rk;
        }

        // ---- O += P V via K=16 MFMAs; V B-frags read ONCE, shared by strips ----
        #pragma unroll
        for (int t = 0; t < 4; ++t) {
            #pragma unroll
            for (int et = 0; et < 4; ++et) {
                bf16x4 vb4 = *(const bf16x4*)&Vc[(et * 16 + m) * KPV + t * 16 + quad * 4];
                O0[et] = mfma16(pa0[t], vb4, O0[et]);
                O1[et] = mfma16(pa1[t], vb4, O1[et]);
            }
        }
    }

    lsum0 += __shfl_xor(lsum0, 16, 64); lsum0 += __shfl_xor(lsum0, 32, 64);
    lsum1 += __shfl_xor(lsum1, 16, 64); lsum1 += __shfl_xor(lsum1, 32, 64);
    if (lane < 16) { lsl[pr0 + lane] = lsum0; lsl[pr1 + lane] = lsum1; }

    __syncthreads();
    {
        const float* mp = mem + (size_t)h * 4096;
        const float* gp = Gv + (size_t)bh * 4096;
        #pragma unroll
        for (int s2 = 0; s2 < 2; ++s2) {
            int idx = s2 * 512 + tid;          // e(64) x d-quad(16)
            int e = idx & 63, d4 = (idx >> 6) << 2;
            bf16x4 mv, gv;
            #pragma unroll
            for (int j = 0; j < 4; ++j) {
                mv[j] = (__bf16)mp[(size_t)(d4 + j) * 64 + e];
                gv[j] = (__bf16)gp[(size_t)(d4 + j) * 64 + e];
            }
            *(bf16x4*)&MT[e * KP + d4] = mv;
            *(bf16x4*)&GT[e * KPV + d4] = gv;
        }
    }
    __syncthreads();

    __bf16* op = o + ((size_t)bh * N_ + n0) * 64;
    #pragma unroll
    for (int s = 0; s < 2; ++s) {
        const int prs = w * 32 + s * 16;
        bf16x8 ea0, ea1;
        #pragma unroll
        for (int j = 0; j < 8; ++j) {
            ea0[j] = (__bf16)eluf((float)(s == 0 ? qa00[j] : qa10[j]));
            ea1[j] = (__bf16)eluf((float)(s == 0 ? qa01[j] : qa11[j]));
        }
        f32x4 num[4];
        #pragma unroll
        for (int t = 0; t < 4; ++t) {
            bf16x8 b0 = *(const bf16x8*)&MT[(t * 16 + m) * KP + quad * 8];
            bf16x8 b1 = *(const bf16x8*)&MT[(t * 16 + m) * KP + 32 + quad * 8];
            f32x4 z = {0.f, 0.f, 0.f, 0.f};
            z = __builtin_amdgcn_mfma_f32_16x16x32_bf16(ea0, b0, z, 0, 0, 0);
            num[t] = __builtin_amdgcn_mfma_f32_16x16x32_bf16(ea1, b1, z, 0, 0, 0);
        }
        *(bf16x8*)&Pw[(prs + m) * KP + quad * 8]      = ea0;
        *(bf16x8*)&Pw[(prs + m) * KP + 32 + quad * 8] = ea1;
        asm volatile("s_waitcnt lgkmcnt(0)" ::: "memory");
        float mq[4][4];
        #pragma unroll
        for (int t = 0; t < 4; ++t)
            #pragma unroll
            for (int r = 0; r < 4; ++r) {
                float eqv = (float)Pw[(prs + quad * 4 + r) * KP + t * 16 + m];
                mq[t][r] = num[t][r] / (eqv * nrm_l[prs + quad * 4 + r]);
            }
        #pragma unroll
        for (int t = 0; t < 4; ++t)
            #pragma unroll
            for (int r = 0; r < 4; ++r)
                Pw[(prs + quad * 4 + r) * KP + t * 16 + m] = (__bf16)mq[t][r];
        asm volatile("s_waitcnt lgkmcnt(0)" ::: "memory");
        bf16x8 ma0 = *(const bf16x8*)&Pw[(prs + m) * KP + quad * 8];
        bf16x8 ma1 = *(const bf16x8*)&Pw[(prs + m) * KP + 32 + quad * 8];

        #pragma unroll
        for (int t = 0; t < 4; ++t) {
            bf16x8 g0 = *(const bf16x8*)&GT[(t * 16 + m) * KPV + quad * 8];
            bf16x8 g1 = *(const bf16x8*)&GT[(t * 16 + m) * KPV + 32 + quad * 8];
            f32x4 z = {0.f, 0.f, 0.f, 0.f};
            z = __builtin_amdgcn_mfma_f32_16x16x32_bf16(ma0, g0, z, 0, 0, 0);
            f32x4 o2 = __builtin_amdgcn_mfma_f32_16x16x32_bf16(ma1, g1, z, 0, 0, 0);
            #pragma unroll
            for (int r = 0; r < 4; ++r) {
                const int qr = prs + quad * 4 + r;
                float val = ((s == 0) ? O0[t][r] : O1[t][r]) * (gl / lsl[qr])
                            + sigg * o2[r];
                op[(size_t)qr * 64 + t * 16 + m] = (__bf16)val;
            }
        }
    }
}

// ---------------- K5: output projection on MFMA (unchanged) ----------------
__global__ __launch_bounds__(256) void k_outproj(
    const __bf16* __restrict__ o, const float* __restrict__ Wo,
    const float* __restrict__ bo, float* __restrict__ out)
{
    const int row0 = blockIdx.x * 64;      // over B*N
    const int b = row0 >> 11, nb = row0 & 2047;
    __shared__ __align__(16) __bf16 WoS[64 * 40];   // [dout][k] per 32-k block
    const int tid  = threadIdx.x;
    const int w    = tid >> 6, lane = tid & 63;
    const int quad = lane >> 4, m = lane & 15;

    f32x4 acc[4];
    #pragma unroll
    for (int t = 0; t < 4; ++t) { f32x4 z = {0.f, 0.f, 0.f, 0.f}; acc[t] = z; }

    for (int kbk = 0; kbk < 16; ++kbk) {
        for (int s2 = 0; s2 < 8; ++s2) {
            int flat = s2 * 256 + tid;      // flat = n*32 + kk
            int n = flat >> 5, kk = flat & 31;
            WoS[n * 40 + kk] = (__bf16)Wo[(size_t)n * 512 + kbk * 32 + kk];
        }
        __syncthreads();
        const int hc = kbk >> 1;
        size_t arow = (((size_t)b * H_ + hc) * N_ + nb + w * 16 + m);
        bf16x8 af = *(const bf16x8*)&o[arow * 64 + (kbk & 1) * 32 + quad * 8];
        #pragma unroll
        for (int t = 0; t < 4; ++t) {
            bf16x8 bf_ = *(const bf16x8*)&WoS[(t * 16 + m) * 40 + quad * 8];
            acc[t] = __builtin_amdgcn_mfma_f32_16x16x32_bf16(af, bf_, acc[t], 0, 0, 0);
        }
        __syncthreads();
    }
    #pragma unroll
    for (int t = 0; t < 4; ++t) {
        float bias = bo[t * 16 + m];
        #pragma unroll
        for (int r = 0; r < 4; ++r)
            out[(size_t)(row0 + w * 16 + quad * 4 + r) * 64 + t * 16 + m] =
                acc[t][r] + bias;
    }
}

extern "C" void kernel_launch(void* const* d_in, const int* in_sizes, int n_in,
                              void* d_out, int out_size, void* d_ws, size_t ws_size,
                              hipStream_t stream)
{
    const float* q        = (const float*)d_in[0];
    const float* k        = (const float*)d_in[1];
    const float* v        = (const float*)d_in[2];
    const float* Wq       = (const float*)d_in[3];
    const float* Wk       = (const float*)d_in[4];
    const float* Wv       = (const float*)d_in[5];
    const float* Wo       = (const float*)d_in[6];
    const float* bo       = (const float*)d_in[7];
    const float* Wg       = (const float*)d_in[8];
    const float* s_local  = (const float*)d_in[9];
    const float* s_long   = (const float*)d_in[10];
    const float* mem      = (const float*)d_in[11];
    const float* mem_norm = (const float*)d_in[12];

    float* ws = (float*)d_ws;
    float*  kh  = ws;
    __bf16* qb  = (__bf16*)(ws + 4194304);
    __bf16* kb  = (__bf16*)(ws + 6291456);
    __bf16* vb  = (__bf16*)(ws + 8388608);
    __bf16* vbT = (__bf16*)(ws + 10485760);
    float*  Gv  = ws + 12582912;
    float*  pm  = ws + 12713984;
    float*  pg  = ws + 14811136;
    __bf16* o   = (__bf16*)(ws + 12713984);   // aliases pm (dead after k_reduce)

    float* out      = (float*)d_out;
    float* out_mem  = out + 524288;
    float* out_norm = out + 655360;

    k_proj   <<<dim3(128, 8, 3), 256, 0, stream>>>(q, k, v, Wq, Wk, Wv,
                                                   qb, kh, kb, vb, vbT);
    k_memacc <<<dim3(16, 32),    256, 0, stream>>>(kh, vb, mem, mem_norm,
                                                   pm, out_norm);
    k_gv     <<<dim3(16, 32),    256, 0, stream>>>(Wg, vbT, pg);
    k_reduce <<<dim3(512),       256, 0, stream>>>(mem, pm, pg, out_mem, Gv);
    k_flash  <<<dim3(8, 32),     512, 0, stream>>>(qb, kb, vbT, mem, mem_norm, Gv,
                                                   s_local, s_long, o);
    k_outproj<<<dim3(128),       256, 0, stream>>>(o, Wo, bo, out);
}